// Round 10
// baseline (60.459 us; speedup 1.0000x reference)
//
#include <hip/hip_runtime.h>

#define KK 5
#define RR 2
#define N_ 2
#define C_ 256
#define H_ 128
#define W_ 128
#define H2 256
#define W2 256
#define TH 16
#define TW 16
#define CCHUNK 8
#define CG 4                 // chunk-iterations per block (32 channels total)
#define PH 20
#define PW 20
#define PHPW 400
#define HW (H_*W_)
#define HW2 (H2*W2)
#define DEPTH 4              // mask prefetch ring depth
#define BUFW (2*PHPW*4)      // 3200 words per LDS buffer

__device__ __forceinline__ void stage_issue(const float* __restrict__ fbase,
                                            int gy0, int gx0, int tid, float4 vr[4]) {
    #pragma unroll
    for (int r = 0; r < 4; ++r) {
        const int idx = tid + r * 256;
        vr[r] = make_float4(0.f, 0.f, 0.f, 0.f);
        if (idx < 2 * PHPW) {
            const int G  = idx / PHPW;          // channel-quad plane 0/1
            const int p  = idx - G * PHPW;
            const int py = p / PW;
            const int px = p - py * PW;
            const int gy = gy0 + py;
            const int gx = gx0 + px;
            if ((unsigned)gy < (unsigned)H_ && (unsigned)gx < (unsigned)W_) {
                const float* fp = fbase + (4 * G) * HW + gy * W_ + gx;
                vr[r].x = fp[0];
                vr[r].y = fp[HW];
                vr[r].z = fp[2 * HW];
                vr[r].w = fp[3 * HW];
            }
        }
    }
}

__device__ __forceinline__ void stage_write(float* __restrict__ buf,
                                            int tid, const float4 vr[4]) {
    #pragma unroll
    for (int r = 0; r < 4; ++r) {
        const int idx = tid + r * 256;
        if (idx < 2 * PHPW) {
            const int G = idx / PHPW;
            const int p = idx - G * PHPW;
            *reinterpret_cast<float4*>(&buf[G * 1600 + p * 4]) = vr[r];
        }
    }
}

__global__ __launch_bounds__(256) void carafe_kernel(
    const float* __restrict__ feat,
    const float* __restrict__ masks,
    float* __restrict__ out)
{
    // Channel-group-planar per buffer: word = G*1600 + p*4 + t (channel 4G+t,
    // pixel p). b128 reads/writes land 8 words/bank = conflict floor.
    __shared__ float patch[2 * BUFW];   // 25600 B, double-buffered

    const int tid = threadIdx.x;
    const int tx = tid & 15;
    const int ty = tid >> 4;
    const int bx = blockIdx.x & 7;     // W_/TW = 8
    const int by = blockIdx.x >> 3;    // H_/TH = 8
    const int c_base = blockIdx.y * (CCHUNK * CG);
    const int n  = blockIdx.z;

    const int i0 = by * TH + ty;
    const int j0 = bx * TW + tx;
    const int gy0 = by * TH - RR;
    const int gx0 = bx * TW - RR;

    const float* mb = masks + ((size_t)n * (KK * KK) * H2 + (size_t)(2 * i0)) * W2 + 2 * j0;
    const int p0 = ty * PW + tx;

    // ---- prologue: ring preload (oldest), then stage chunk 0 ----
    float2 q0[DEPTH], q1[DEPTH];
    #pragma unroll
    for (int t = 0; t < DEPTH; ++t) {
        q0[t] = *reinterpret_cast<const float2*>(mb + (size_t)t * HW2);
        q1[t] = *reinterpret_cast<const float2*>(mb + (size_t)t * HW2 + W2);
    }
    float4 vr[4];
    stage_issue(feat + (size_t)(n * C_ + c_base) * HW, gy0, gx0, tid, vr);
    stage_write(patch, tid, vr);
    __syncthreads();

    for (int cg = 0; cg < CG; ++cg) {   // rolled: keeps hot loop I-cache-resident
        if (cg > 0) {                   // re-preload ring (L2-hot after cg 0)
            #pragma unroll
            for (int t = 0; t < DEPTH; ++t) {
                q0[t] = *reinterpret_cast<const float2*>(mb + (size_t)t * HW2);
                q1[t] = *reinterpret_cast<const float2*>(mb + (size_t)t * HW2 + W2);
            }
        }
        // issue next chunk's gather loads; latency hides under the k-loop
        if (cg + 1 < CG)
            stage_issue(feat + (size_t)(n * C_ + c_base + (cg + 1) * CCHUNK) * HW,
                        gy0, gx0, tid, vr);

        const float* bp = &patch[(cg & 1) * BUFW];
        float acc[CCHUNK][2][2] = {};

        #pragma unroll
        for (int k = 0; k < KK * KK; ++k) {
            const float2 m0 = q0[k % DEPTH];   // static index after unroll
            const float2 m1 = q1[k % DEPTH];
            if (k + DEPTH < KK * KK) {
                q0[k % DEPTH] = *reinterpret_cast<const float2*>(mb + (size_t)(k + DEPTH) * HW2);
                q1[k % DEPTH] = *reinterpret_cast<const float2*>(mb + (size_t)(k + DEPTH) * HW2 + W2);
            }
            const int dy = k / KK;
            const int dx = k - KK * dy;
            const int P  = p0 + dy * PW + dx;
            const float4 v0 = *reinterpret_cast<const float4*>(&bp[P * 4]);
            const float4 v1 = *reinterpret_cast<const float4*>(&bp[1600 + P * 4]);

            acc[0][0][0] += v0.x * m0.x;  acc[0][0][1] += v0.x * m0.y;
            acc[0][1][0] += v0.x * m1.x;  acc[0][1][1] += v0.x * m1.y;
            acc[1][0][0] += v0.y * m0.x;  acc[1][0][1] += v0.y * m0.y;
            acc[1][1][0] += v0.y * m1.x;  acc[1][1][1] += v0.y * m1.y;
            acc[2][0][0] += v0.z * m0.x;  acc[2][0][1] += v0.z * m0.y;
            acc[2][1][0] += v0.z * m1.x;  acc[2][1][1] += v0.z * m1.y;
            acc[3][0][0] += v0.w * m0.x;  acc[3][0][1] += v0.w * m0.y;
            acc[3][1][0] += v0.w * m1.x;  acc[3][1][1] += v0.w * m1.y;
            acc[4][0][0] += v1.x * m0.x;  acc[4][0][1] += v1.x * m0.y;
            acc[4][1][0] += v1.x * m1.x;  acc[4][1][1] += v1.x * m1.y;
            acc[5][0][0] += v1.y * m0.x;  acc[5][0][1] += v1.y * m0.y;
            acc[5][1][0] += v1.y * m1.x;  acc[5][1][1] += v1.y * m1.y;
            acc[6][0][0] += v1.z * m0.x;  acc[6][0][1] += v1.z * m0.y;
            acc[6][1][0] += v1.z * m1.x;  acc[6][1][1] += v1.z * m1.y;
            acc[7][0][0] += v1.w * m0.x;  acc[7][0][1] += v1.w * m0.y;
            acc[7][1][0] += v1.w * m1.x;  acc[7][1][1] += v1.w * m1.y;
        }

        // store this chunk: 8 channels x 2x2 quad
        float* ob = out + ((size_t)(n * C_ + c_base + cg * CCHUNK) * H2 + (size_t)(2 * i0)) * W2 + 2 * j0;
        #pragma unroll
        for (int c = 0; c < CCHUNK; ++c) {
            *reinterpret_cast<float2*>(ob)      = make_float2(acc[c][0][0], acc[c][0][1]);
            *reinterpret_cast<float2*>(ob + W2) = make_float2(acc[c][1][0], acc[c][1][1]);
            ob += (size_t)HW2;
        }

        if (cg + 1 < CG) {
            __syncthreads();   // all waves done reading the buffer we overwrite
            stage_write(&patch[((cg + 1) & 1) * BUFW], tid, vr);
            __syncthreads();   // writes visible before next k-loop
        }
    }
}

extern "C" void kernel_launch(void* const* d_in, const int* in_sizes, int n_in,
                              void* d_out, int out_size, void* d_ws, size_t ws_size,
                              hipStream_t stream) {
    const float* feat  = (const float*)d_in[0];
    const float* masks = (const float*)d_in[1];
    float* out = (float*)d_out;

    dim3 grid((W_ / TW) * (H_ / TH),       // 64 spatial tiles
              C_ / (CCHUNK * CG),          // 8 chunk-groups
              N_);                         // 2 batch
    carafe_kernel<<<grid, dim3(256), 0, stream>>>(feat, masks, out);
}